// Round 4
// baseline (392.829 us; speedup 1.0000x reference)
//
#include <hip/hip_runtime.h>
#include <hip/hip_bf16.h>

#define B_SZ    2
#define S_LEN   2048
#define D_MODEL 2048
#define N_HEADS 16
#define D_HEAD  128
#define L_RANK  64
#define M_ROWS  (B_SZ * S_LEN)   // 4096
#define KD      2048             // GEMM K
#define NT      (KD / 32)        // 64 K-steps

typedef short          bf16x8 __attribute__((ext_vector_type(8)));
typedef float          f32x4  __attribute__((ext_vector_type(4)));
typedef float          f32x16 __attribute__((ext_vector_type(16)));
typedef unsigned short us4v   __attribute__((ext_vector_type(4)));
typedef unsigned short us8v   __attribute__((ext_vector_type(8)));
typedef unsigned int   u32x4  __attribute__((ext_vector_type(4)));

// log2(e) / sqrt(128), folded into the Q projection epilogue
#define SCALE_Q 0.127517432f

static __device__ __forceinline__ unsigned short f2bf(float f) {
    unsigned int u = __float_as_uint(f);
    u += 0x7FFFu + ((u >> 16) & 1u);      // RNE; inputs finite
    return (unsigned short)(u >> 16);
}

static __device__ __forceinline__ void gload16(const void* g, void* l) {
    __builtin_amdgcn_global_load_lds(
        (const __attribute__((address_space(1))) unsigned int*)g,
        (__attribute__((address_space(3))) unsigned int*)l, 16, 0, 0);
}

static __device__ __forceinline__ float exp2_hw(float x) {
    float r; asm("v_exp_f32 %0, %1" : "=v"(r) : "v"(x)); return r;
}
static __device__ __forceinline__ unsigned int cvtpk_bf16(float a, float b) {
    unsigned int r; asm("v_cvt_pk_bf16_f32 %0, %1, %2" : "=v"(r) : "v"(a), "v"(b)); return r;
}

// ---------------------------------------------------------------------------
// W [K][N] fp32 -> WT [N][K] bf16 (Wq and Wo), 64x64 LDS tile transpose
// ---------------------------------------------------------------------------
__global__ __launch_bounds__(256) void transpose_w_kernel(
    const float* __restrict__ Wq, const float* __restrict__ Wo,
    unsigned short* __restrict__ WqT, unsigned short* __restrict__ WoT)
{
    const float* W = blockIdx.z ? Wo : Wq;
    unsigned short* WT = blockIdx.z ? WoT : WqT;
    const int k0 = blockIdx.y * 64, n0 = blockIdx.x * 64;
    const int tid = threadIdx.x;
    __shared__ float t[64][69];
    #pragma unroll
    for (int c = 0; c < 4; ++c) {
        int idx = c * 256 + tid;
        int r = idx >> 4, c4 = (idx & 15) * 4;
        float4 v = *(const float4*)&W[(size_t)(k0 + r) * D_MODEL + n0 + c4];
        t[r][c4] = v.x; t[r][c4 + 1] = v.y; t[r][c4 + 2] = v.z; t[r][c4 + 3] = v.w;
    }
    __syncthreads();
    #pragma unroll
    for (int c = 0; c < 2; ++c) {
        int idx = c * 256 + tid;
        int nr = idx >> 3, s = idx & 7;
        us8v o;
        #pragma unroll
        for (int j = 0; j < 8; ++j) o[j] = f2bf(t[s * 8 + j][nr]);
        *(us8v*)&WT[(size_t)(n0 + nr) * D_MODEL + k0 + s * 8] = o;
    }
}

// ---------------------------------------------------------------------------
// WeT[h*128+d][din] = sum_l Wl[din][h*64+l] * Wr[l][d]  (bf16, transposed out)
// ---------------------------------------------------------------------------
__global__ __launch_bounds__(256) void weff_t_kernel(
    const float* __restrict__ Wlk, const float* __restrict__ Wlv,
    const float* __restrict__ Wkr, const float* __restrict__ Wvr,
    const float* __restrict__ blk, const float* __restrict__ blv,
    const float* __restrict__ bkr, const float* __restrict__ bvr,
    unsigned short* __restrict__ WeTk, unsigned short* __restrict__ WeTv,
    float* __restrict__ beffk, float* __restrict__ beffv)
{
    const int z = blockIdx.z;
    const float* Wl = z ? Wlv : Wlk;
    const float* Wr = z ? Wvr : Wkr;
    const float* bl = z ? blv : blk;
    const float* br = z ? bvr : bkr;
    unsigned short* We = z ? WeTv : WeTk;
    float* be = z ? beffv : beffk;

    const int h = blockIdx.y;
    const int din0 = blockIdx.x * 64;
    const int tid = threadIdx.x;
    const int lane = tid & 63, w = tid >> 6;

    __shared__ float WrS[64][128];   // [l][d]
    __shared__ float WlT[64][65];    // [l][r]

    #pragma unroll
    for (int c = 0; c < 8; ++c) {
        int e = c * 1024 + tid * 4;
        int l = e >> 7, d = e & 127;
        *(float4*)&WrS[l][d] = *(const float4*)&Wr[l * D_HEAD + d];
    }
    #pragma unroll
    for (int c = 0; c < 4; ++c) {
        int idx = c * 256 + tid;
        int r = idx >> 4, l4 = (idx & 15) * 4;
        float4 v = *(const float4*)&Wl[(size_t)(din0 + r) * (L_RANK * N_HEADS) + h * L_RANK + l4];
        WlT[l4 + 0][r] = v.x; WlT[l4 + 1][r] = v.y; WlT[l4 + 2][r] = v.z; WlT[l4 + 3][r] = v.w;
    }
    __syncthreads();

    for (int i = 0; i < 32; ++i) {
        int d = i * 4 + w;
        float acc = 0.f;
        #pragma unroll
        for (int l = 0; l < L_RANK; ++l) acc += WlT[l][lane] * WrS[l][d];
        We[(size_t)(h * D_HEAD + d) * D_MODEL + din0 + lane] = f2bf(acc);
    }
    if (blockIdx.x == 0 && tid < D_HEAD) {
        float acc = br[tid];
        #pragma unroll
        for (int l = 0; l < L_RANK; ++l) acc += bl[h * L_RANK + l] * WrS[l][tid];
        be[h * D_HEAD + tid] = acc;
    }
}

// ---------------------------------------------------------------------------
// Batched projection GEMM: z in {0:Q, 1:K, 2:V}.
// C_z = cvt_bf16(A_z fp32 [4096][2048]) @ Bt_z[N][K]^T bf16 + bias_z.
// A reg-staged (fp32 load -> cvt -> ds_write), B via global_load_lds; both
// double-buffered; ONE barrier per K-step (stage t+1 issued before MFMA t).
// z=0 out bf16 *SCALE_Q; z=1 out bf16; z=2 out v_t[(b*16+h)*128+d][s].
// grid: 1536 flat blocks, XCD-bijective swizzle.
// ---------------------------------------------------------------------------
__global__ __launch_bounds__(256) void proj_gemm_kernel(
    const float* __restrict__ queries, const float* __restrict__ keys,
    const float* __restrict__ values,
    const unsigned short* __restrict__ WqT, const unsigned short* __restrict__ WeTk,
    const unsigned short* __restrict__ WeTv,
    const float* __restrict__ bq, const float* __restrict__ beffk,
    const float* __restrict__ beffv,
    unsigned short* __restrict__ q_bf, unsigned short* __restrict__ k_bf,
    unsigned short* __restrict__ v_t)
{
    __shared__ unsigned short Al[2][128 * 32];
    __shared__ unsigned short Bl[2][128 * 32];

    const int flat = blockIdx.x;
    const int swz = (flat & 7) * 192 + (flat >> 3);   // 1536 = 8 * 192
    const int z = swz >> 9;
    const int rem = swz & 511;
    const int row0 = (rem >> 4) * 128, col0 = (rem & 15) * 128;

    const float*          A    = z == 0 ? queries : (z == 1 ? keys : values);
    const unsigned short* Bt   = z == 0 ? WqT     : (z == 1 ? WeTk : WeTv);
    const float*          bias = z == 0 ? bq      : (z == 1 ? beffk : beffv);

    const int tid = threadIdx.x;
    const int lane = tid & 63, wid = tid >> 6;
    const int lr = lane & 15, lg = lane >> 4;
    const int wr = wid >> 1, wc = wid & 1;

    // --- A staging geometry: thread covers rows {r0, r0+64}, 8 floats each
    const int r0 = tid >> 2;
    const int c8 = (tid & 3) * 8;
    const int aphys = (((tid & 3) ^ ((r0 >> 1) & 3))) * 8;   // swizzled 16B chunk
    const float* ap0 = A + (size_t)(row0 + r0) * KD + c8;
    const float* ap1 = ap0 + (size_t)64 * KD;

    // --- B staging geometry (global_load_lds, chunk-swizzled source)
    const unsigned short* bg[2];
    unsigned short* blp[2][2];
    #pragma unroll
    for (int c = 0; c < 2; ++c) {
        int idx = wid * 128 + c * 64 + lane;
        int row = idx >> 2, p = idx & 3;
        int sp = p ^ ((row >> 1) & 3);
        bg[c] = Bt + (size_t)(col0 + row) * KD + sp * 8;
        blp[0][c] = Bl[0] + idx * 8;
        blp[1][c] = Bl[1] + idx * 8;
    }
    const int sx = (lr >> 1) & 3;
    const int abase = (wr * 64 + lr) * 32 + ((lg ^ sx) * 8);
    const int bbase = (wc * 64 + lr) * 32 + ((lg ^ sx) * 8);

    f32x4 acc[4][4];
    #pragma unroll
    for (int m = 0; m < 4; ++m)
        #pragma unroll
        for (int n = 0; n < 4; ++n) acc[m][n] = (f32x4){0.f, 0.f, 0.f, 0.f};

    // ---- prologue: tile 0 ----
    {
        float4 a0 = *(const float4*)ap0;
        float4 a1 = *(const float4*)(ap0 + 4);
        float4 a2 = *(const float4*)ap1;
        float4 a3 = *(const float4*)(ap1 + 4);
        #pragma unroll
        for (int c = 0; c < 2; ++c) gload16(bg[c], blp[0][c]);
        us8v w0 = { f2bf(a0.x), f2bf(a0.y), f2bf(a0.z), f2bf(a0.w),
                    f2bf(a1.x), f2bf(a1.y), f2bf(a1.z), f2bf(a1.w) };
        us8v w1 = { f2bf(a2.x), f2bf(a2.y), f2bf(a2.z), f2bf(a2.w),
                    f2bf(a3.x), f2bf(a3.y), f2bf(a3.z), f2bf(a3.w) };
        *(us8v*)&Al[0][r0 * 32 + aphys] = w0;
        *(us8v*)&Al[0][(r0 + 64) * 32 + aphys] = w1;
    }
    __syncthreads();

    // ---- main loop: one barrier per K-step ----
    #pragma unroll 1
    for (int t = 0; t < NT; ++t) {
        const int cur = t & 1, nxt = cur ^ 1;
        float4 a0, a1, a2, a3;
        const bool more = (t + 1 < NT);
        if (more) {
            const float* p0 = ap0 + (size_t)(t + 1) * 32;
            const float* p1 = ap1 + (size_t)(t + 1) * 32;
            a0 = *(const float4*)p0; a1 = *(const float4*)(p0 + 4);
            a2 = *(const float4*)p1; a3 = *(const float4*)(p1 + 4);
            #pragma unroll
            for (int c = 0; c < 2; ++c) gload16(bg[c] + (size_t)(t + 1) * 32, blp[nxt][c]);
        }

        bf16x8 af[4], bfv[4];
        #pragma unroll
        for (int m = 0; m < 4; ++m) af[m]  = *(const bf16x8*)&Al[cur][abase + m * 512];
        #pragma unroll
        for (int n = 0; n < 4; ++n) bfv[n] = *(const bf16x8*)&Bl[cur][bbase + n * 512];
        __builtin_amdgcn_s_setprio(1);
        #pragma unroll
        for (int m = 0; m < 4; ++m)
            #pragma unroll
            for (int n = 0; n < 4; ++n)
                acc[m][n] = __builtin_amdgcn_mfma_f32_16x16x32_bf16(af[m], bfv[n], acc[m][n], 0, 0, 0);
        __builtin_amdgcn_s_setprio(0);

        if (more) {
            us8v w0 = { f2bf(a0.x), f2bf(a0.y), f2bf(a0.z), f2bf(a0.w),
                        f2bf(a1.x), f2bf(a1.y), f2bf(a1.z), f2bf(a1.w) };
            us8v w1 = { f2bf(a2.x), f2bf(a2.y), f2bf(a2.z), f2bf(a2.w),
                        f2bf(a3.x), f2bf(a3.y), f2bf(a3.z), f2bf(a3.w) };
            *(us8v*)&Al[nxt][r0 * 32 + aphys] = w0;
            *(us8v*)&Al[nxt][(r0 + 64) * 32 + aphys] = w1;
        }
        __syncthreads();
    }

    // ---- epilogue ----
    float bv[4];
    #pragma unroll
    for (int n = 0; n < 4; ++n) bv[n] = bias[col0 + wc * 64 + n * 16 + lr];
    const float omul = (z == 0) ? SCALE_Q : 1.0f;

    #pragma unroll
    for (int m = 0; m < 4; ++m) {
        #pragma unroll
        for (int n = 0; n < 4; ++n) {
            const int col = col0 + wc * 64 + n * 16 + lr;
            const int rowb = row0 + wr * 64 + m * 16 + lg * 4;
            if (z < 2) {
                unsigned short* C = z == 0 ? q_bf : k_bf;
                #pragma unroll
                for (int j = 0; j < 4; ++j)
                    C[(size_t)(rowb + j) * D_MODEL + col] = f2bf((acc[m][n][j] + bv[n]) * omul);
            } else {
                const int bidx = rowb >> 11, s = rowb & 2047;
                const int h = col >> 7, d = col & 127;
                us4v o = { f2bf(acc[m][n][0] + bv[n]), f2bf(acc[m][n][1] + bv[n]),
                           f2bf(acc[m][n][2] + bv[n]), f2bf(acc[m][n][3] + bv[n]) };
                *(us4v*)&v_t[((size_t)(bidx * 16 + h) * 128 + d) * 2048 + s] = o;
            }
        }
    }
}

// ---------------------------------------------------------------------------
// Output GEMM: out fp32 = ao[4096][2048] bf16 @ WoT[N][K]^T bf16 + bo.
// Same single-barrier double-buffered structure, both operands via gload_lds.
// ---------------------------------------------------------------------------
__global__ __launch_bounds__(256) void out_gemm_kernel(
    const unsigned short* __restrict__ A,
    const unsigned short* __restrict__ Bt,
    const float* __restrict__ bias,
    float* __restrict__ C)
{
    __shared__ unsigned short Al[2][128 * 32];
    __shared__ unsigned short Bl[2][128 * 32];

    const int flat = blockIdx.x;
    const int swz = (flat & 7) * 64 + (flat >> 3);   // 512 = 8 * 64
    const int row0 = (swz >> 4) * 128, col0 = (swz & 15) * 128;

    const int tid = threadIdx.x;
    const int lane = tid & 63, wid = tid >> 6;
    const int lr = lane & 15, lg = lane >> 4;
    const int wr = wid >> 1, wc = wid & 1;

    const unsigned short* ag[2];
    const unsigned short* bg[2];
    unsigned short* alp[2][2];
    unsigned short* blp[2][2];
    #pragma unroll
    for (int c = 0; c < 2; ++c) {
        int idx = wid * 128 + c * 64 + lane;
        int row = idx >> 2, p = idx & 3;
        int sp = p ^ ((row >> 1) & 3);
        ag[c] = A  + (size_t)(row0 + row) * KD + sp * 8;
        bg[c] = Bt + (size_t)(col0 + row) * KD + sp * 8;
        alp[0][c] = Al[0] + idx * 8;  alp[1][c] = Al[1] + idx * 8;
        blp[0][c] = Bl[0] + idx * 8;  blp[1][c] = Bl[1] + idx * 8;
    }
    const int sx = (lr >> 1) & 3;
    const int abase = (wr * 64 + lr) * 32 + ((lg ^ sx) * 8);
    const int bbase = (wc * 64 + lr) * 32 + ((lg ^ sx) * 8);

    f32x4 acc[4][4];
    #pragma unroll
    for (int m = 0; m < 4; ++m)
        #pragma unroll
        for (int n = 0; n < 4; ++n) acc[m][n] = (f32x4){0.f, 0.f, 0.f, 0.f};

    #pragma unroll
    for (int c = 0; c < 2; ++c) { gload16(ag[c], alp[0][c]); gload16(bg[c], blp[0][c]); }
    __syncthreads();

    #pragma unroll 1
    for (int t = 0; t < NT; ++t) {
        const int cur = t & 1, nxt = cur ^ 1;
        if (t + 1 < NT) {
            #pragma unroll
            for (int c = 0; c < 2; ++c) {
                gload16(ag[c] + (size_t)(t + 1) * 32, alp[nxt][c]);
                gload16(bg[c] + (size_t)(t + 1) * 32, blp[nxt][c]);
            }
        }
        bf16x8 af[4], bfv[4];
        #pragma unroll
        for (int m = 0; m < 4; ++m) af[m]  = *(const bf16x8*)&Al[cur][abase + m * 512];
        #pragma unroll
        for (int n = 0; n < 4; ++n) bfv[n] = *(const bf16x8*)&Bl[cur][bbase + n * 512];
        __builtin_amdgcn_s_setprio(1);
        #pragma unroll
        for (int m = 0; m < 4; ++m)
            #pragma unroll
            for (int n = 0; n < 4; ++n)
                acc[m][n] = __builtin_amdgcn_mfma_f32_16x16x32_bf16(af[m], bfv[n], acc[m][n], 0, 0, 0);
        __builtin_amdgcn_s_setprio(0);
        __syncthreads();
    }

    float bv[4];
    #pragma unroll
    for (int n = 0; n < 4; ++n) bv[n] = bias[col0 + wc * 64 + n * 16 + lr];
    #pragma unroll
    for (int m = 0; m < 4; ++m)
        #pragma unroll
        for (int n = 0; n < 4; ++n) {
            const int col = col0 + wc * 64 + n * 16 + lr;
            const int rowb = row0 + wr * 64 + m * 16 + lg * 4;
            #pragma unroll
            for (int j = 0; j < 4; ++j)
                C[(size_t)(rowb + j) * D_MODEL + col] = acc[m][n][j] + bv[n];
        }
}

// ---------------------------------------------------------------------------
// Causal flash attention, swapped-QK 32x32x16 structure (unchanged from R3).
// ---------------------------------------------------------------------------
static __device__ __forceinline__ void flash_stage(
    const unsigned short* __restrict__ kgh,
    const unsigned short* __restrict__ vtb,
    unsigned short* Kl, unsigned short* Vl, int kv0, int tid)
{
    #pragma unroll
    for (int c = 0; c < 4; ++c) {
        int idx = c * 256 + tid;
        int r = idx >> 4, ch = idx & 15;
        gload16(kgh + (size_t)(kv0 + r) * D_MODEL + ((ch ^ (r & 7)) * 8), Kl + idx * 8);
    }
    #pragma unroll
    for (int c = 0; c < 4; ++c) {
        int idx = c * 256 + tid;
        int d = idx >> 3, ch = idx & 7;
        gload16(vtb + (size_t)d * S_LEN + kv0 + ((ch ^ (d & 7)) * 8), Vl + idx * 8);
    }
}

__global__ __launch_bounds__(256, 2) void flash_kernel(
    const unsigned short* __restrict__ Q,
    const unsigned short* __restrict__ Kg,
    const unsigned short* __restrict__ Vt,
    unsigned short* __restrict__ Og)
{
    __shared__ unsigned short Klds[2][64 * 128];
    __shared__ unsigned short Vlds[2][128 * 64];

    const int tid = threadIdx.x;
    const int lane = tid & 63, wid = tid >> 6;
    const int lc = lane & 31, hi = lane >> 5;

    const int blk = blockIdx.x;
    const int jj = blk >> 5;
    const int qt = (jj < 8) ? jj : 23 - jj;
    const int bh = blk & 31;
    const int b = bh >> 4, h = bh & 15;
    const size_t base = (size_t)b * S_LEN * D_MODEL;
    const unsigned short* kgh = Kg + base + h * D_HEAD;
    const unsigned short* vtb = Vt + (size_t)bh * D_HEAD * S_LEN;

    const int q0w = qt * 128 + wid * 32;
    const int qcol = q0w + lc;

    bf16x8 qf[8];
    #pragma unroll
    for (int dc = 0; dc < 8; ++dc)
        qf[dc] = *(const bf16x8*)&Q[base + (size_t)qcol * D_MODEL + h * D_HEAD + dc * 16 + hi * 8];

    f32x16 o_acc[4];
    #pragma unroll
    for (int dt = 0; dt < 4; ++dt)
        #pragma unroll
        for (int r = 0; r < 16; ++r) o_acc[dt][r] = 0.f;
    float m_r = -3e38f, l_r = 0.f;

    const int kxor = lc & 7;
    const int nt = 2 * qt + 2;

    flash_stage(kgh, vtb, Klds[0], Vlds[0], 0, tid);

    #pragma unroll 1
    for (int t = 0; t < nt; ++t) {
        const int bb = t & 1;
        const int kv0 = t * 64;
        __syncthreads();
        if (t + 1 < nt)
            flash_stage(kgh, vtb, Klds[bb ^ 1], Vlds[bb ^ 1], (t + 1) * 64, tid);

        f32x16 s0, s1;
        #pragma unroll
        for (int r = 0; r < 16; ++r) { s0[r] = 0.f; s1[r] = 0.f; }
        __builtin_amdgcn_s_setprio(1);
        #pragma unroll
        for (int dc = 0; dc < 8; ++dc) {
            bf16x8 kf = *(const bf16x8*)&Klds[bb][lc * 128 + (((dc * 2 + hi) ^ kxor) * 8)];
            s0 = __builtin_amdgcn_mfma_f32_32x32x16_bf16(kf, qf[dc], s0, 0, 0, 0);
        }
        #pragma unroll
        for (int dc = 0; dc < 8; ++dc) {
            bf16x8 kf = *(const bf16x8*)&Klds[bb][(32 + lc) * 128 + (((dc * 2 + hi) ^ kxor) * 8)];
            s1 = __builtin_amdgcn_mfma_f32_32x32x16_bf16(kf, qf[dc], s1, 0, 0, 0);
        }
        __builtin_amdgcn_s_setprio(0);

        if (t >= nt - 2) {
            #pragma unroll
            for (int r = 0; r < 16; ++r) {
                int krow = (r & 3) + 8 * (r >> 2) + 4 * hi;
                if (kv0 + krow > qcol)      s0[r] = -3e38f;
                if (kv0 + 32 + krow > qcol) s1[r] = -3e38f;
            }
        }

        float mt[8];
        #pragma unroll
        for (int i = 0; i < 8; ++i)
            mt[i] = fmaxf(fmaxf(s0[2 * i], s0[2 * i + 1]), fmaxf(s1[2 * i], s1[2 * i + 1]));
        float mA = fmaxf(fmaxf(mt[0], mt[1]), fmaxf(mt[2], mt[3]));
        float mB = fmaxf(fmaxf(mt[4], mt[5]), fmaxf(mt[6], mt[7]));
        float sm = fmaxf(mA, mB);
        sm = fmaxf(sm, __shfl_xor(sm, 32));

        if (__any(sm > m_r + 11.5f)) {
            float mnew = fmaxf(m_r, sm);
            float alpha = exp2_hw(m_r - mnew);
            l_r *= alpha;
            m_r = mnew;
            #pragma unroll
            for (int r = 0; r < 16; ++r) {
                float av = __shfl(alpha, (r & 3) + 8 * (r >> 2) + 4 * hi);
                #pragma unroll
                for (int dt = 0; dt < 4; ++dt) o_acc[dt][r] *= av;
            }
        }

        #pragma unroll
        for (int r = 0; r < 16; ++r) {
            s0[r] = exp2_hw(s0[r] - m_r);
            s1[r] = exp2_hw(s1[r] - m_r);
        }
        float st[8];
        #pragma unroll
        for (int i = 0; i < 8; ++i)
            st[i] = (s0[2 * i] + s0[2 * i + 1]) + (s1[2 * i] + s1[2 * i + 1]);
        l_r += ((st[0] + st[1]) + (st[2] + st[3])) + ((st[4] + st[5]) + (st[6] + st[7]));

        #pragma unroll
        for (int t32 = 0; t32 < 2; ++t32) {
            const f32x16& s = t32 ? s1 : s0;
            unsigned int c0[4], c1[4];
            #pragma unroll
            for (int g = 0; g < 4; ++g) {
                c0[g] = cvtpk_bf16(s[4 * g],     s[4 * g + 1]);
                c1[g] = cvtpk_bf16(s[4 * g + 2], s[4 * g + 3]);
            }
            #pragma unroll
            for (int kt = 0; kt < 2; ++kt) {
                unsigned int sel0 = hi ? c0[2 * kt] : c0[2 * kt + 1];
                unsigned int sel1 = hi ? c1[2 * kt] : c1[2 * kt + 1];
                unsigned int o0 = (unsigned int)__shfl_xor((int)sel0, 32);
                unsigned int o1 = (unsigned int)__shfl_xor((int)sel1, 32);
                u32x4 uu;
                uu.x = hi ? o0 : c0[2 * kt];
                uu.y = hi ? o1 : c1[2 * kt];
                uu.z = hi ? c0[2 * kt + 1] : o0;
                uu.w = hi ? c1[2 * kt + 1] : o1;
                bf16x8 pf = __builtin_bit_cast(bf16x8, uu);
                __builtin_amdgcn_s_setprio(1);
                #pragma unroll
                for (int dt = 0; dt < 4; ++dt) {
                    bf16x8 vf = *(const bf16x8*)
                        &Vlds[bb][(dt * 32 + lc) * 64 + (((t32 * 4 + kt * 2 + hi) ^ kxor) * 8)];
                    o_acc[dt] = __builtin_amdgcn_mfma_f32_32x32x16_bf16(pf, vf, o_acc[dt], 0, 0, 0);
                }
                __builtin_amdgcn_s_setprio(0);
            }
        }
    }

    float lt = l_r + __shfl_xor(l_r, 32);
    float inv = 1.0f / lt;
    #pragma unroll
    for (int r = 0; r < 16; ++r) {
        int qrow = (r & 3) + 8 * (r >> 2) + 4 * hi;
        float iv = __shfl(inv, qrow);
        #pragma unroll
        for (int dt = 0; dt < 4; ++dt)
            Og[base + (size_t)(q0w + qrow) * D_MODEL + h * D_HEAD + dt * 32 + lc] =
                f2bf(o_acc[dt][r] * iv);
    }
}

// ---------------------------------------------------------------------------
extern "C" void kernel_launch(void* const* d_in, const int* in_sizes, int n_in,
                              void* d_out, int out_size, void* d_ws, size_t ws_size,
                              hipStream_t stream)
{
    const float* queries = (const float*)d_in[0];
    const float* keys    = (const float*)d_in[1];
    const float* values  = (const float*)d_in[2];
    const float* Wq  = (const float*)d_in[3];
    const float* bq  = (const float*)d_in[4];
    const float* Wlk = (const float*)d_in[5];
    const float* blk = (const float*)d_in[6];
    const float* Wlv = (const float*)d_in[7];
    const float* blv = (const float*)d_in[8];
    const float* Wkr = (const float*)d_in[9];
    const float* bkr = (const float*)d_in[10];
    const float* Wvr = (const float*)d_in[11];
    const float* bvr = (const float*)d_in[12];
    const float* Wo  = (const float*)d_in[13];
    const float* bo  = (const float*)d_in[14];
    float* out = (float*)d_out;

    char* ws = (char*)d_ws;
    const size_t MB16 = (size_t)M_ROWS * D_MODEL * 2;       // 16 MB
    const size_t MB8  = (size_t)D_MODEL * D_MODEL * 2;      // 8 MB
    unsigned short* q_bf = (unsigned short*)(ws);
    unsigned short* k_bf = (unsigned short*)(ws + MB16);
    unsigned short* v_t  = (unsigned short*)(ws + 2 * MB16);
    unsigned short* ao   = (unsigned short*)(ws + 3 * MB16);
    unsigned short* WqT  = (unsigned short*)(ws + 4 * MB16);
    unsigned short* WeTk = (unsigned short*)(ws + 4 * MB16 + MB8);
    unsigned short* WeTv = (unsigned short*)(ws + 4 * MB16 + 2 * MB8);
    unsigned short* WoT  = (unsigned short*)(ws + 4 * MB16 + 3 * MB8);
    float* beffk = (float*)(ws + 4 * MB16 + 4 * MB8);
    float* beffv = beffk + D_MODEL;

    weff_t_kernel<<<dim3(32, 16, 2), 256, 0, stream>>>(
        Wlk, Wlv, Wkr, Wvr, blk, blv, bkr, bvr, WeTk, WeTv, beffk, beffv);
    transpose_w_kernel<<<dim3(32, 32, 2), 256, 0, stream>>>(Wq, Wo, WqT, WoT);

    proj_gemm_kernel<<<1536, 256, 0, stream>>>(
        queries, keys, values, WqT, WeTk, WeTv, bq, beffk, beffv,
        q_bf, k_bf, v_t);

    flash_kernel<<<512, 256, 0, stream>>>(q_bf, k_bf, v_t, ao);

    out_gemm_kernel<<<512, 256, 0, stream>>>(ao, WoT, bo, out);
}

// Round 5
// 332.943 us; speedup vs baseline: 1.1799x; 1.1799x over previous
//
#include <hip/hip_runtime.h>
#include <hip/hip_bf16.h>

#define B_SZ    2
#define S_LEN   2048
#define D_MODEL 2048
#define N_HEADS 16
#define D_HEAD  128
#define L_RANK  64
#define M_ROWS  (B_SZ * S_LEN)   // 4096
#define KD      2048             // GEMM K
#define NT      (KD / 32)        // 64 K-steps

typedef short          bf16x8 __attribute__((ext_vector_type(8)));
typedef float          f32x4  __attribute__((ext_vector_type(4)));
typedef float          f32x16 __attribute__((ext_vector_type(16)));
typedef unsigned short us4v   __attribute__((ext_vector_type(4)));
typedef unsigned short us8v   __attribute__((ext_vector_type(8)));
typedef unsigned int   u32x4  __attribute__((ext_vector_type(4)));

// log2(e) / sqrt(128), folded into the Q projection epilogue
#define SCALE_Q 0.127517432f

static __device__ __forceinline__ unsigned short f2bf(float f) {
    unsigned int u = __float_as_uint(f);
    u += 0x7FFFu + ((u >> 16) & 1u);      // RNE; inputs finite
    return (unsigned short)(u >> 16);
}

static __device__ __forceinline__ void gload16(const void* g, void* l) {
    __builtin_amdgcn_global_load_lds(
        (const __attribute__((address_space(1))) unsigned int*)g,
        (__attribute__((address_space(3))) unsigned int*)l, 16, 0, 0);
}

static __device__ __forceinline__ float exp2_hw(float x) {
    float r; asm("v_exp_f32 %0, %1" : "=v"(r) : "v"(x)); return r;
}
static __device__ __forceinline__ unsigned int cvtpk_bf16(float a, float b) {
    unsigned int r; asm("v_cvt_pk_bf16_f32 %0, %1, %2" : "=v"(r) : "v"(a), "v"(b)); return r;
}

// ---------------------------------------------------------------------------
// fp32 -> bf16 for all three activation tensors in ONE dispatch.
// grid 12288: z = bid >> 12 selects tensor; 4096 blocks each.
// ---------------------------------------------------------------------------
__global__ __launch_bounds__(256) void conv3_kernel(
    const float* __restrict__ q_in, const float* __restrict__ k_in,
    const float* __restrict__ v_in,
    unsigned short* __restrict__ q_o, unsigned short* __restrict__ k_o,
    unsigned short* __restrict__ v_o)
{
    const int bid = blockIdx.x;
    const int z = bid >> 12;               // 4096 blocks per tensor
    const float* in = z == 0 ? q_in : (z == 1 ? k_in : v_in);
    unsigned short* out = z == 0 ? q_o : (z == 1 ? k_o : v_o);
    size_t i = ((size_t)(bid & 4095) * 256 + threadIdx.x) * 8;
    float4 a = *(const float4*)&in[i];
    float4 b = *(const float4*)&in[i + 4];
    us8v o = { f2bf(a.x), f2bf(a.y), f2bf(a.z), f2bf(a.w),
               f2bf(b.x), f2bf(b.y), f2bf(b.z), f2bf(b.w) };
    *(us8v*)&out[i] = o;
}

// ---------------------------------------------------------------------------
// W [K][N] fp32 -> WT [N][K] bf16 (Wq and Wo), 64x64 LDS tile transpose
// ---------------------------------------------------------------------------
__global__ __launch_bounds__(256) void transpose_w_kernel(
    const float* __restrict__ Wq, const float* __restrict__ Wo,
    unsigned short* __restrict__ WqT, unsigned short* __restrict__ WoT)
{
    const float* W = blockIdx.z ? Wo : Wq;
    unsigned short* WT = blockIdx.z ? WoT : WqT;
    const int k0 = blockIdx.y * 64, n0 = blockIdx.x * 64;
    const int tid = threadIdx.x;
    __shared__ float t[64][69];
    #pragma unroll
    for (int c = 0; c < 4; ++c) {
        int idx = c * 256 + tid;
        int r = idx >> 4, c4 = (idx & 15) * 4;
        float4 v = *(const float4*)&W[(size_t)(k0 + r) * D_MODEL + n0 + c4];
        t[r][c4] = v.x; t[r][c4 + 1] = v.y; t[r][c4 + 2] = v.z; t[r][c4 + 3] = v.w;
    }
    __syncthreads();
    #pragma unroll
    for (int c = 0; c < 2; ++c) {
        int idx = c * 256 + tid;
        int nr = idx >> 3, s = idx & 7;
        us8v o;
        #pragma unroll
        for (int j = 0; j < 8; ++j) o[j] = f2bf(t[s * 8 + j][nr]);
        *(us8v*)&WT[(size_t)(n0 + nr) * D_MODEL + k0 + s * 8] = o;
    }
}

// ---------------------------------------------------------------------------
// WeT[h*128+d][din] = sum_l Wl[din][h*64+l] * Wr[l][d]  (bf16, transposed out)
// ---------------------------------------------------------------------------
__global__ __launch_bounds__(256) void weff_t_kernel(
    const float* __restrict__ Wlk, const float* __restrict__ Wlv,
    const float* __restrict__ Wkr, const float* __restrict__ Wvr,
    const float* __restrict__ blk, const float* __restrict__ blv,
    const float* __restrict__ bkr, const float* __restrict__ bvr,
    unsigned short* __restrict__ WeTk, unsigned short* __restrict__ WeTv,
    float* __restrict__ beffk, float* __restrict__ beffv)
{
    const int z = blockIdx.z;
    const float* Wl = z ? Wlv : Wlk;
    const float* Wr = z ? Wvr : Wkr;
    const float* bl = z ? blv : blk;
    const float* br = z ? bvr : bkr;
    unsigned short* We = z ? WeTv : WeTk;
    float* be = z ? beffv : beffk;

    const int h = blockIdx.y;
    const int din0 = blockIdx.x * 64;
    const int tid = threadIdx.x;
    const int lane = tid & 63, w = tid >> 6;

    __shared__ float WrS[64][128];   // [l][d]
    __shared__ float WlT[64][65];    // [l][r]

    #pragma unroll
    for (int c = 0; c < 8; ++c) {
        int e = c * 1024 + tid * 4;
        int l = e >> 7, d = e & 127;
        *(float4*)&WrS[l][d] = *(const float4*)&Wr[l * D_HEAD + d];
    }
    #pragma unroll
    for (int c = 0; c < 4; ++c) {
        int idx = c * 256 + tid;
        int r = idx >> 4, l4 = (idx & 15) * 4;
        float4 v = *(const float4*)&Wl[(size_t)(din0 + r) * (L_RANK * N_HEADS) + h * L_RANK + l4];
        WlT[l4 + 0][r] = v.x; WlT[l4 + 1][r] = v.y; WlT[l4 + 2][r] = v.z; WlT[l4 + 3][r] = v.w;
    }
    __syncthreads();

    for (int i = 0; i < 32; ++i) {
        int d = i * 4 + w;
        float acc = 0.f;
        #pragma unroll
        for (int l = 0; l < L_RANK; ++l) acc += WlT[l][lane] * WrS[l][d];
        We[(size_t)(h * D_HEAD + d) * D_MODEL + din0 + lane] = f2bf(acc);
    }
    if (blockIdx.x == 0 && tid < D_HEAD) {
        float acc = br[tid];
        #pragma unroll
        for (int l = 0; l < L_RANK; ++l) acc += bl[h * L_RANK + l] * WrS[l][tid];
        be[h * D_HEAD + tid] = acc;
    }
}

// ---------------------------------------------------------------------------
// Batched projection GEMM: z in {0:Q, 1:K, 2:V}, both operands bf16 via
// global_load_lds (chunk-swizzled sources), double-buffered, ONE barrier
// per K-step (prefetch t+1 issued before MFMA t).
// z=0 out bf16 *SCALE_Q; z=1 out bf16; z=2 out v_t[(b*16+h)*128+d][s].
// grid 1536, XCD-bijective swizzle.
// ---------------------------------------------------------------------------
__global__ __launch_bounds__(256) void proj_gemm_kernel(
    const unsigned short* __restrict__ Aq, const unsigned short* __restrict__ Ak,
    const unsigned short* __restrict__ Av,
    const unsigned short* __restrict__ WqT, const unsigned short* __restrict__ WeTk,
    const unsigned short* __restrict__ WeTv,
    const float* __restrict__ bq, const float* __restrict__ beffk,
    const float* __restrict__ beffv,
    unsigned short* __restrict__ q_bf, unsigned short* __restrict__ k_bf,
    unsigned short* __restrict__ v_t)
{
    __shared__ unsigned short Al[2][128 * 32];
    __shared__ unsigned short Bl[2][128 * 32];

    const int flat = blockIdx.x;
    const int swz = (flat & 7) * 192 + (flat >> 3);   // 1536 = 8 * 192
    const int z = swz >> 9;
    const int rem = swz & 511;
    const int row0 = (rem >> 4) * 128, col0 = (rem & 15) * 128;

    const unsigned short* A    = z == 0 ? Aq  : (z == 1 ? Ak   : Av);
    const unsigned short* Bt   = z == 0 ? WqT : (z == 1 ? WeTk : WeTv);
    const float*          bias = z == 0 ? bq  : (z == 1 ? beffk : beffv);

    const int tid = threadIdx.x;
    const int lane = tid & 63, wid = tid >> 6;
    const int lr = lane & 15, lg = lane >> 4;
    const int wr = wid >> 1, wc = wid & 1;

    const unsigned short* ag[2];
    const unsigned short* bg[2];
    unsigned short* alp[2][2];
    unsigned short* blp[2][2];
    #pragma unroll
    for (int c = 0; c < 2; ++c) {
        int idx = wid * 128 + c * 64 + lane;
        int row = idx >> 2, p = idx & 3;
        int sp = p ^ ((row >> 1) & 3);
        ag[c] = A  + (size_t)(row0 + row) * KD + sp * 8;
        bg[c] = Bt + (size_t)(col0 + row) * KD + sp * 8;
        alp[0][c] = Al[0] + idx * 8;  alp[1][c] = Al[1] + idx * 8;
        blp[0][c] = Bl[0] + idx * 8;  blp[1][c] = Bl[1] + idx * 8;
    }
    const int sx = (lr >> 1) & 3;
    const int abase = (wr * 64 + lr) * 32 + ((lg ^ sx) * 8);
    const int bbase = (wc * 64 + lr) * 32 + ((lg ^ sx) * 8);

    f32x4 acc[4][4];
    #pragma unroll
    for (int m = 0; m < 4; ++m)
        #pragma unroll
        for (int n = 0; n < 4; ++n) acc[m][n] = (f32x4){0.f, 0.f, 0.f, 0.f};

    #pragma unroll
    for (int c = 0; c < 2; ++c) { gload16(ag[c], alp[0][c]); gload16(bg[c], blp[0][c]); }
    __syncthreads();

    #pragma unroll 1
    for (int t = 0; t < NT; ++t) {
        const int cur = t & 1, nxt = cur ^ 1;
        if (t + 1 < NT) {
            #pragma unroll
            for (int c = 0; c < 2; ++c) {
                gload16(ag[c] + (size_t)(t + 1) * 32, alp[nxt][c]);
                gload16(bg[c] + (size_t)(t + 1) * 32, blp[nxt][c]);
            }
        }
        bf16x8 af[4], bfv[4];
        #pragma unroll
        for (int m = 0; m < 4; ++m) af[m]  = *(const bf16x8*)&Al[cur][abase + m * 512];
        #pragma unroll
        for (int n = 0; n < 4; ++n) bfv[n] = *(const bf16x8*)&Bl[cur][bbase + n * 512];
        __builtin_amdgcn_s_setprio(1);
        #pragma unroll
        for (int m = 0; m < 4; ++m)
            #pragma unroll
            for (int n = 0; n < 4; ++n)
                acc[m][n] = __builtin_amdgcn_mfma_f32_16x16x32_bf16(af[m], bfv[n], acc[m][n], 0, 0, 0);
        __builtin_amdgcn_s_setprio(0);
        __syncthreads();
    }

    float bv[4];
    #pragma unroll
    for (int n = 0; n < 4; ++n) bv[n] = bias[col0 + wc * 64 + n * 16 + lr];
    const float omul = (z == 0) ? SCALE_Q : 1.0f;

    #pragma unroll
    for (int m = 0; m < 4; ++m) {
        #pragma unroll
        for (int n = 0; n < 4; ++n) {
            const int col = col0 + wc * 64 + n * 16 + lr;
            const int rowb = row0 + wr * 64 + m * 16 + lg * 4;
            if (z < 2) {
                unsigned short* C = z == 0 ? q_bf : k_bf;
                #pragma unroll
                for (int j = 0; j < 4; ++j)
                    C[(size_t)(rowb + j) * D_MODEL + col] = f2bf((acc[m][n][j] + bv[n]) * omul);
            } else {
                const int bidx = rowb >> 11, s = rowb & 2047;
                const int h = col >> 7, d = col & 127;
                us4v o = { f2bf(acc[m][n][0] + bv[n]), f2bf(acc[m][n][1] + bv[n]),
                           f2bf(acc[m][n][2] + bv[n]), f2bf(acc[m][n][3] + bv[n]) };
                *(us4v*)&v_t[((size_t)(bidx * 16 + h) * 128 + d) * 2048 + s] = o;
            }
        }
    }
}

// ---------------------------------------------------------------------------
// Output GEMM: out fp32 = ao[4096][2048] bf16 @ WoT[N][K]^T bf16 + bo.
// ---------------------------------------------------------------------------
__global__ __launch_bounds__(256) void out_gemm_kernel(
    const unsigned short* __restrict__ A,
    const unsigned short* __restrict__ Bt,
    const float* __restrict__ bias,
    float* __restrict__ C)
{
    __shared__ unsigned short Al[2][128 * 32];
    __shared__ unsigned short Bl[2][128 * 32];

    const int flat = blockIdx.x;
    const int swz = (flat & 7) * 64 + (flat >> 3);   // 512 = 8 * 64
    const int row0 = (swz >> 4) * 128, col0 = (swz & 15) * 128;

    const int tid = threadIdx.x;
    const int lane = tid & 63, wid = tid >> 6;
    const int lr = lane & 15, lg = lane >> 4;
    const int wr = wid >> 1, wc = wid & 1;

    const unsigned short* ag[2];
    const unsigned short* bg[2];
    unsigned short* alp[2][2];
    unsigned short* blp[2][2];
    #pragma unroll
    for (int c = 0; c < 2; ++c) {
        int idx = wid * 128 + c * 64 + lane;
        int row = idx >> 2, p = idx & 3;
        int sp = p ^ ((row >> 1) & 3);
        ag[c] = A  + (size_t)(row0 + row) * KD + sp * 8;
        bg[c] = Bt + (size_t)(col0 + row) * KD + sp * 8;
        alp[0][c] = Al[0] + idx * 8;  alp[1][c] = Al[1] + idx * 8;
        blp[0][c] = Bl[0] + idx * 8;  blp[1][c] = Bl[1] + idx * 8;
    }
    const int sx = (lr >> 1) & 3;
    const int abase = (wr * 64 + lr) * 32 + ((lg ^ sx) * 8);
    const int bbase = (wc * 64 + lr) * 32 + ((lg ^ sx) * 8);

    f32x4 acc[4][4];
    #pragma unroll
    for (int m = 0; m < 4; ++m)
        #pragma unroll
        for (int n = 0; n < 4; ++n) acc[m][n] = (f32x4){0.f, 0.f, 0.f, 0.f};

    #pragma unroll
    for (int c = 0; c < 2; ++c) { gload16(ag[c], alp[0][c]); gload16(bg[c], blp[0][c]); }
    __syncthreads();

    #pragma unroll 1
    for (int t = 0; t < NT; ++t) {
        const int cur = t & 1, nxt = cur ^ 1;
        if (t + 1 < NT) {
            #pragma unroll
            for (int c = 0; c < 2; ++c) {
                gload16(ag[c] + (size_t)(t + 1) * 32, alp[nxt][c]);
                gload16(bg[c] + (size_t)(t + 1) * 32, blp[nxt][c]);
            }
        }
        bf16x8 af[4], bfv[4];
        #pragma unroll
        for (int m = 0; m < 4; ++m) af[m]  = *(const bf16x8*)&Al[cur][abase + m * 512];
        #pragma unroll
        for (int n = 0; n < 4; ++n) bfv[n] = *(const bf16x8*)&Bl[cur][bbase + n * 512];
        __builtin_amdgcn_s_setprio(1);
        #pragma unroll
        for (int m = 0; m < 4; ++m)
            #pragma unroll
            for (int n = 0; n < 4; ++n)
                acc[m][n] = __builtin_amdgcn_mfma_f32_16x16x32_bf16(af[m], bfv[n], acc[m][n], 0, 0, 0);
        __builtin_amdgcn_s_setprio(0);
        __syncthreads();
    }

    float bv[4];
    #pragma unroll
    for (int n = 0; n < 4; ++n) bv[n] = bias[col0 + wc * 64 + n * 16 + lr];
    #pragma unroll
    for (int m = 0; m < 4; ++m)
        #pragma unroll
        for (int n = 0; n < 4; ++n) {
            const int col = col0 + wc * 64 + n * 16 + lr;
            const int rowb = row0 + wr * 64 + m * 16 + lg * 4;
            #pragma unroll
            for (int j = 0; j < 4; ++j)
                C[(size_t)(rowb + j) * D_MODEL + col] = acc[m][n][j] + bv[n];
        }
}

// ---------------------------------------------------------------------------
// Causal flash attention, swapped-QK 32x32x16, QK dependent-chain split 4-way.
// ---------------------------------------------------------------------------
static __device__ __forceinline__ void flash_stage(
    const unsigned short* __restrict__ kgh,
    const unsigned short* __restrict__ vtb,
    unsigned short* Kl, unsigned short* Vl, int kv0, int tid)
{
    #pragma unroll
    for (int c = 0; c < 4; ++c) {
        int idx = c * 256 + tid;
        int r = idx >> 4, ch = idx & 15;
        gload16(kgh + (size_t)(kv0 + r) * D_MODEL + ((ch ^ (r & 7)) * 8), Kl + idx * 8);
    }
    #pragma unroll
    for (int c = 0; c < 4; ++c) {
        int idx = c * 256 + tid;
        int d = idx >> 3, ch = idx & 7;
        gload16(vtb + (size_t)d * S_LEN + kv0 + ((ch ^ (d & 7)) * 8), Vl + idx * 8);
    }
}

__global__ __launch_bounds__(256, 2) void flash_kernel(
    const unsigned short* __restrict__ Q,
    const unsigned short* __restrict__ Kg,
    const unsigned short* __restrict__ Vt,
    unsigned short* __restrict__ Og)
{
    __shared__ unsigned short Klds[2][64 * 128];
    __shared__ unsigned short Vlds[2][128 * 64];

    const int tid = threadIdx.x;
    const int lane = tid & 63, wid = tid >> 6;
    const int lc = lane & 31, hi = lane >> 5;

    const int blk = blockIdx.x;
    const int jj = blk >> 5;
    const int qt = (jj < 8) ? jj : 23 - jj;
    const int bh = blk & 31;
    const int b = bh >> 4, h = bh & 15;
    const size_t base = (size_t)b * S_LEN * D_MODEL;
    const unsigned short* kgh = Kg + base + h * D_HEAD;
    const unsigned short* vtb = Vt + (size_t)bh * D_HEAD * S_LEN;

    const int q0w = qt * 128 + wid * 32;
    const int qcol = q0w + lc;

    bf16x8 qf[8];
    #pragma unroll
    for (int dc = 0; dc < 8; ++dc)
        qf[dc] = *(const bf16x8*)&Q[base + (size_t)qcol * D_MODEL + h * D_HEAD + dc * 16 + hi * 8];

    f32x16 o_acc[4];
    #pragma unroll
    for (int dt = 0; dt < 4; ++dt)
        #pragma unroll
        for (int r = 0; r < 16; ++r) o_acc[dt][r] = 0.f;
    float m_r = -3e38f, l_r = 0.f;

    const int kxor = lc & 7;
    const int nt = 2 * qt + 2;

    flash_stage(kgh, vtb, Klds[0], Vlds[0], 0, tid);

    #pragma unroll 1
    for (int t = 0; t < nt; ++t) {
        const int bb = t & 1;
        const int kv0 = t * 64;
        __syncthreads();
        if (t + 1 < nt)
            flash_stage(kgh, vtb, Klds[bb ^ 1], Vlds[bb ^ 1], (t + 1) * 64, tid);

        // ---- S^T = K Q^T: 4 independent accumulator chains ----
        f32x16 s0a, s0b, s1a, s1b;
        #pragma unroll
        for (int r = 0; r < 16; ++r) { s0a[r] = 0.f; s0b[r] = 0.f; s1a[r] = 0.f; s1b[r] = 0.f; }
        __builtin_amdgcn_s_setprio(1);
        #pragma unroll
        for (int dc = 0; dc < 4; ++dc) {
            bf16x8 kf0 = *(const bf16x8*)&Klds[bb][lc * 128 + (((dc * 2 + hi) ^ kxor) * 8)];
            bf16x8 kf1 = *(const bf16x8*)&Klds[bb][(32 + lc) * 128 + (((dc * 2 + hi) ^ kxor) * 8)];
            s0a = __builtin_amdgcn_mfma_f32_32x32x16_bf16(kf0, qf[dc], s0a, 0, 0, 0);
            s1a = __builtin_amdgcn_mfma_f32_32x32x16_bf16(kf1, qf[dc], s1a, 0, 0, 0);
        }
        #pragma unroll
        for (int dc = 4; dc < 8; ++dc) {
            bf16x8 kf0 = *(const bf16x8*)&Klds[bb][lc * 128 + (((dc * 2 + hi) ^ kxor) * 8)];
            bf16x8 kf1 = *(const bf16x8*)&Klds[bb][(32 + lc) * 128 + (((dc * 2 + hi) ^ kxor) * 8)];
            s0b = __builtin_amdgcn_mfma_f32_32x32x16_bf16(kf0, qf[dc], s0b, 0, 0, 0);
            s1b = __builtin_amdgcn_mfma_f32_32x32x16_bf16(kf1, qf[dc], s1b, 0, 0, 0);
        }
        __builtin_amdgcn_s_setprio(0);
        f32x16 s0 = s0a + s0b;
        f32x16 s1 = s1a + s1b;

        if (t >= nt - 2) {
            #pragma unroll
            for (int r = 0; r < 16; ++r) {
                int krow = (r & 3) + 8 * (r >> 2) + 4 * hi;
                if (kv0 + krow > qcol)      s0[r] = -3e38f;
                if (kv0 + 32 + krow > qcol) s1[r] = -3e38f;
            }
        }

        float mt[8];
        #pragma unroll
        for (int i = 0; i < 8; ++i)
            mt[i] = fmaxf(fmaxf(s0[2 * i], s0[2 * i + 1]), fmaxf(s1[2 * i], s1[2 * i + 1]));
        float mA = fmaxf(fmaxf(mt[0], mt[1]), fmaxf(mt[2], mt[3]));
        float mB = fmaxf(fmaxf(mt[4], mt[5]), fmaxf(mt[6], mt[7]));
        float sm = fmaxf(mA, mB);
        sm = fmaxf(sm, __shfl_xor(sm, 32));

        if (__any(sm > m_r + 11.5f)) {
            float mnew = fmaxf(m_r, sm);
            float alpha = exp2_hw(m_r - mnew);
            l_r *= alpha;
            m_r = mnew;
            #pragma unroll
            for (int r = 0; r < 16; ++r) {
                float av = __shfl(alpha, (r & 3) + 8 * (r >> 2) + 4 * hi);
                #pragma unroll
                for (int dt = 0; dt < 4; ++dt) o_acc[dt][r] *= av;
            }
        }

        #pragma unroll
        for (int r = 0; r < 16; ++r) {
            s0[r] = exp2_hw(s0[r] - m_r);
            s1[r] = exp2_hw(s1[r] - m_r);
        }
        float st[8];
        #pragma unroll
        for (int i = 0; i < 8; ++i)
            st[i] = (s0[2 * i] + s0[2 * i + 1]) + (s1[2 * i] + s1[2 * i + 1]);
        l_r += ((st[0] + st[1]) + (st[2] + st[3])) + ((st[4] + st[5]) + (st[6] + st[7]));

        #pragma unroll
        for (int t32 = 0; t32 < 2; ++t32) {
            const f32x16& s = t32 ? s1 : s0;
            unsigned int c0[4], c1[4];
            #pragma unroll
            for (int g = 0; g < 4; ++g) {
                c0[g] = cvtpk_bf16(s[4 * g],     s[4 * g + 1]);
                c1[g] = cvtpk_bf16(s[4 * g + 2], s[4 * g + 3]);
            }
            #pragma unroll
            for (int kt = 0; kt < 2; ++kt) {
                unsigned int sel0 = hi ? c0[2 * kt] : c0[2 * kt + 1];
                unsigned int sel1 = hi ? c1[2 * kt] : c1[2 * kt + 1];
                unsigned int o0 = (unsigned int)__shfl_xor((int)sel0, 32);
                unsigned int o1 = (unsigned int)__shfl_xor((int)sel1, 32);
                u32x4 uu;
                uu.x = hi ? o0 : c0[2 * kt];
                uu.y = hi ? o1 : c1[2 * kt];
                uu.z = hi ? c0[2 * kt + 1] : o0;
                uu.w = hi ? c1[2 * kt + 1] : o1;
                bf16x8 pf = __builtin_bit_cast(bf16x8, uu);
                __builtin_amdgcn_s_setprio(1);
                #pragma unroll
                for (int dt = 0; dt < 4; ++dt) {
                    bf16x8 vf = *(const bf16x8*)
                        &Vlds[bb][(dt * 32 + lc) * 64 + (((t32 * 4 + kt * 2 + hi) ^ kxor) * 8)];
                    o_acc[dt] = __builtin_amdgcn_mfma_f32_32x32x16_bf16(pf, vf, o_acc[dt], 0, 0, 0);
                }
                __builtin_amdgcn_s_setprio(0);
            }
        }
    }

    float lt = l_r + __shfl_xor(l_r, 32);
    float inv = 1.0f / lt;
    #pragma unroll
    for (int r = 0; r < 16; ++r) {
        int qrow = (r & 3) + 8 * (r >> 2) + 4 * hi;
        float iv = __shfl(inv, qrow);
        #pragma unroll
        for (int dt = 0; dt < 4; ++dt)
            Og[base + (size_t)(q0w + qrow) * D_MODEL + h * D_HEAD + dt * 32 + lc] =
                f2bf(o_acc[dt][r] * iv);
    }
}

// ---------------------------------------------------------------------------
extern "C" void kernel_launch(void* const* d_in, const int* in_sizes, int n_in,
                              void* d_out, int out_size, void* d_ws, size_t ws_size,
                              hipStream_t stream)
{
    const float* queries = (const float*)d_in[0];
    const float* keys    = (const float*)d_in[1];
    const float* values  = (const float*)d_in[2];
    const float* Wq  = (const float*)d_in[3];
    const float* bq  = (const float*)d_in[4];
    const float* Wlk = (const float*)d_in[5];
    const float* blk = (const float*)d_in[6];
    const float* Wlv = (const float*)d_in[7];
    const float* blv = (const float*)d_in[8];
    const float* Wkr = (const float*)d_in[9];
    const float* bkr = (const float*)d_in[10];
    const float* Wvr = (const float*)d_in[11];
    const float* bvr = (const float*)d_in[12];
    const float* Wo  = (const float*)d_in[13];
    const float* bo  = (const float*)d_in[14];
    float* out = (float*)d_out;

    char* ws = (char*)d_ws;
    const size_t MB16 = (size_t)M_ROWS * D_MODEL * 2;       // 16 MB
    const size_t MB8  = (size_t)D_MODEL * D_MODEL * 2;      // 8 MB
    unsigned short* abf_q = (unsigned short*)(ws);
    unsigned short* abf_k = (unsigned short*)(ws + MB16);
    unsigned short* abf_v = (unsigned short*)(ws + 2 * MB16);
    unsigned short* q_bf  = (unsigned short*)(ws + 3 * MB16);
    unsigned short* k_bf  = (unsigned short*)(ws + 4 * MB16);
    unsigned short* v_t   = (unsigned short*)(ws + 5 * MB16);
    unsigned short* ao    = abf_q;                            // dead after proj
    unsigned short* WqT   = (unsigned short*)(ws + 6 * MB16);
    unsigned short* WeTk  = (unsigned short*)(ws + 6 * MB16 + MB8);
    unsigned short* WeTv  = (unsigned short*)(ws + 6 * MB16 + 2 * MB8);
    unsigned short* WoT   = (unsigned short*)(ws + 6 * MB16 + 3 * MB8);
    float* beffk = (float*)(ws + 6 * MB16 + 4 * MB8);
    float* beffv = beffk + D_MODEL;

    weff_t_kernel<<<dim3(32, 16, 2), 256, 0, stream>>>(
        Wlk, Wlv, Wkr, Wvr, blk, blv, bkr, bvr, WeTk, WeTv, beffk, beffv);
    transpose_w_kernel<<<dim3(32, 32, 2), 256, 0, stream>>>(Wq, Wo, WqT, WoT);

    conv3_kernel<<<12288, 256, 0, stream>>>(queries, keys, values, abf_q, abf_k, abf_v);

    proj_gemm_kernel<<<1536, 256, 0, stream>>>(
        abf_q, abf_k, abf_v, WqT, WeTk, WeTv, bq, beffk, beffv,
        q_bf, k_bf, v_t);

    flash_kernel<<<512, 256, 0, stream>>>(q_bf, k_bf, v_t, ao);

    out_gemm_kernel<<<512, 256, 0, stream>>>(ao, WoT, bo, out);
}